// Round 7
// baseline (427.838 us; speedup 1.0000x reference)
//
#include <hip/hip_runtime.h>
#include <hip/hip_bf16.h>

#define DIN 64
#define DH 128
#define EPSF 1e-5f
#define SLOPE 0.1f
#define NCOPY 8

typedef unsigned short u16;
typedef unsigned int u32;
typedef unsigned long long u64;

#define FIXS 16777216.0f   // 2^24 fixed-point scale for edge weights

__device__ __forceinline__ float bf2f(u16 u){
    union { u32 i; float f; } v; v.i = ((u32)u) << 16; return v.f;
}
__device__ __forceinline__ u16 f2bf(float f){
    union { float f; u32 i; } v; v.f = f;
    u32 b = v.i;
    b += 0x7FFFu + ((b >> 16) & 1u);    // round to nearest even
    return (u16)(b >> 16);
}
__device__ __forceinline__ u32 pack2(float a, float b){
    return (u32)f2bf(a) | ((u32)f2bf(b) << 16);
}

// ---------------- graph prep ----------------

__global__ void k_init(u64* packed8, float* stats, int n8){
    int i = blockIdx.x * 256 + threadIdx.x;
    if (i < n8) packed8[i] = 0ull;
    if (i < 4 * DH) stats[i] = 0.0f;           // sum0, sq0, sum1, sq1
}

// ONE returning u64 atomic per edge into an 8-way replicated histogram
// (copy = blockIdx&7, copy-major layout -> 8x fewer same-line serializations).
// count in bits[40..], fixed-point ew sum in bits[0..40).
__global__ void k_count(const int* __restrict__ dst, const float* __restrict__ ew,
                        u64* packed8, int* __restrict__ slotl, int E, int N){
    int e = blockIdx.x * 256 + threadIdx.x;
    if (e < E){
        int d = dst[e];
        int c = blockIdx.x & (NCOPY - 1);
        u64 add = (1ull << 40) | (u64)(u32)__float2int_rn(ew[e] * FIXS);
        u64 old = atomicAdd(&packed8[(size_t)c * N + d], add);
        slotl[e] = (c << 24) | (int)(old >> 40);
    }
}

// phase 1: reduce 8 copies -> deg/dinv, per-copy offsets; block-local scan of counts
__global__ __launch_bounds__(1024) void k_scan1d(const u64* __restrict__ packed8,
        float* __restrict__ dinv, int* __restrict__ rowstart, int* __restrict__ coff,
        int* __restrict__ blocksum, int N){
    __shared__ int lds[1024];
    int t = threadIdx.x;
    int i = blockIdx.x * 1024 + t;
    int v = 0;
    if (i < N){
        u64 fsum = 0;
        int cnt = 0;
        #pragma unroll
        for (int c = 0; c < NCOPY; c++){
            u64 p = packed8[(size_t)c * N + i];
            coff[(size_t)c * N + i] = cnt;         // offset before copy c
            cnt  += (int)(p >> 40);
            fsum += (p & 0xFFFFFFFFFFull);
        }
        float deg = 1.0f + (float)fsum * (1.0f / FIXS);
        dinv[i] = rsqrtf(deg);                     // deg >= 1 (self-loop)
        v = cnt;
    }
    lds[t] = v;
    __syncthreads();
    for (int off = 1; off < 1024; off <<= 1){
        int add = (t >= off) ? lds[t - off] : 0;
        __syncthreads();
        lds[t] += add;
        __syncthreads();
    }
    if (i < N) rowstart[i] = lds[t] - v;            // block-local exclusive
    if (t == 1023) blocksum[blockIdx.x] = lds[1023];
}

// phase 2: scan block sums (nb <= 1024), set rowstart[N]
__global__ __launch_bounds__(1024) void k_scan2(int* __restrict__ blocksum,
        int* __restrict__ rowstart, int nb, int N, int E){
    __shared__ int lds[1024];
    int t = threadIdx.x;
    int v = (t < nb) ? blocksum[t] : 0;
    lds[t] = v;
    __syncthreads();
    for (int off = 1; off < 1024; off <<= 1){
        int add = (t >= off) ? lds[t - off] : 0;
        __syncthreads();
        lds[t] += add;
        __syncthreads();
    }
    if (t < nb) blocksum[t] = lds[t] - v;           // exclusive block offsets
    if (t == 0) rowstart[N] = E;
}

// phase 3: add block offsets
__global__ __launch_bounds__(1024) void k_scan3(int* __restrict__ rowstart,
        const int* __restrict__ blocksum, int N){
    int i = blockIdx.x * 1024 + threadIdx.x;
    if (i < N) rowstart[i] += blocksum[blockIdx.x];
}

// place edge data: slot = rowstart[d] + coff[c][d] + old; NO atomics.
__global__ void k_place(const int* __restrict__ src, const int* __restrict__ dst,
                        const float* __restrict__ ew, const float* __restrict__ dinv,
                        const int* __restrict__ rowst, const int* __restrict__ coff,
                        const int* __restrict__ slotl, u64* __restrict__ edata, int E, int N){
    int e = blockIdx.x * 256 + threadIdx.x;
    if (e < E){
        int s = src[e], d = dst[e];
        int sl = slotl[e];
        int c = sl >> 24, o = sl & 0xFFFFFF;
        union { float f; u32 i; } cf;
        cf.f = dinv[s] * ew[e] * dinv[d];
        int slot = rowst[d] + coff[(size_t)c * N + d] + o;
        edata[slot] = (u64)(u32)s | ((u64)cf.i << 32);
    }
}

// ---------------- GEMMs (f32 VALU, activation tile in LDS, weights via L1/L2) ----------------

// h0 = x @ W0 ; res = x @ Wres + bres.  16 rows/block, 256 threads = 256 out cols (128 | 128).
__global__ __launch_bounds__(256) void k_gemm0(const float* __restrict__ x,
        const float* __restrict__ W0, const float* __restrict__ Wres,
        const float* __restrict__ bres, u16* __restrict__ h0,
        u16* __restrict__ res, int N){
    __shared__ float xs[16 * DIN];              // 4 KB
    int tid = threadIdx.x;
    int row0 = blockIdx.x * 16;
    for (int i = tid; i < 16 * DIN; i += 256){
        int r = i >> 6, k = i & 63;
        int rr = row0 + r; if (rr >= N) rr = N - 1;
        xs[i] = x[(size_t)rr * DIN + k];
    }
    __syncthreads();
    int c = tid & 127;
    const float* __restrict__ W = (tid < DH) ? W0 : Wres;
    float acc[16];
    #pragma unroll
    for (int r = 0; r < 16; r++) acc[r] = 0.0f;
    for (int k = 0; k < DIN; k++){
        float wk = W[k * DH + c];
        #pragma unroll
        for (int r = 0; r < 16; r++) acc[r] += xs[r * DIN + k] * wk;
    }
    if (tid < DH){
        for (int r = 0; r < 16; r++)
            if (row0 + r < N) h0[(size_t)(row0 + r) * DH + c] = f2bf(acc[r]);
    } else {
        float bb = bres[c];
        for (int r = 0; r < 16; r++)
            if (row0 + r < N) res[(size_t)(row0 + r) * DH + c] = f2bf(acc[r] + bb);
    }
}

// A = (leaky(B*scale+shift)+R) @ W1 — BN apply + leaky + residual fused into tile load.
__global__ __launch_bounds__(256) void k_gemm1f(const u16* __restrict__ B,
        const u16* __restrict__ R, const float* __restrict__ sum,
        const float* __restrict__ sq, const float* __restrict__ g,
        const float* __restrict__ be, const float* __restrict__ W1,
        u16* __restrict__ A, int N, float invN){
    __shared__ float xs[16 * DH];               // 8 KB
    __shared__ float sc[DH], sh[DH];
    int tid = threadIdx.x;
    if (tid < DH){
        float mean = sum[tid] * invN;
        float var  = sq[tid] * invN - mean * mean;
        float s = g[tid] * rsqrtf(var + EPSF);
        sc[tid] = s;
        sh[tid] = be[tid] - mean * s;
    }
    __syncthreads();
    int row0 = blockIdx.x * 16;
    for (int i = tid; i < 16 * DH; i += 256){
        int r = i >> 7, k = i & 127;
        int rr = row0 + r;
        float xv = 0.0f;
        if (rr < N){
            float t = bf2f(B[(size_t)rr * DH + k]) * sc[k] + sh[k];
            t = (t >= 0.0f) ? t : SLOPE * t;
            xv = t + bf2f(R[(size_t)rr * DH + k]);
        }
        xs[i] = xv;
    }
    __syncthreads();
    int c = tid & 127, rg = tid >> 7;
    float acc[8];
    #pragma unroll
    for (int r = 0; r < 8; r++) acc[r] = 0.0f;
    for (int k = 0; k < DH; k++){
        float wk = W1[k * DH + c];
        #pragma unroll
        for (int r = 0; r < 8; r++) acc[r] += xs[(rg + 2 * r) * DH + k] * wk;
    }
    #pragma unroll
    for (int r = 0; r < 8; r++){
        int rr = row0 + rg + 2 * r;
        if (rr < N) A[(size_t)rr * DH + c] = f2bf(acc[r]);
    }
}

// ---------------- aggregation: TWO waves per node over CSR halves ----------------
// 512 threads = 8 waves = 4 nodes x 2 half-lists. 4 gather chains/node in flight.

__global__ __launch_bounds__(512) void k_aggregate(const u16* __restrict__ hin,
        u16* __restrict__ out, const float* __restrict__ bias,
        const float* __restrict__ dinv, const int* __restrict__ rowstart,
        const u64* __restrict__ edata, int N){
    __shared__ float part[4][64][2];
    int tid = threadIdx.x;
    int wave = tid >> 6, lane = tid & 63;
    int local = wave >> 1, half = wave & 1;
    int node = blockIdx.x * 4 + local;
    int col = 2 * lane;
    float ax = 0.0f, ay = 0.0f;
    if (node < N){
        int rs = rowstart[node], re = rowstart[node + 1];
        int mid = rs + ((re - rs + 1) >> 1);
        int j  = half ? mid : rs;
        int j1 = half ? re  : mid;
        for (; j + 1 < j1; j += 2){
            u64 e0 = edata[j], e1 = edata[j + 1];
            union { u32 i; float f; } c0, c1;
            c0.i = (u32)(e0 >> 32); c1.i = (u32)(e1 >> 32);
            u32 u0 = *(const u32*)&hin[(size_t)(u32)e0 * DH + col];
            u32 u1 = *(const u32*)&hin[(size_t)(u32)e1 * DH + col];
            ax += c0.f * bf2f((u16)u0) + c1.f * bf2f((u16)u1);
            ay += c0.f * bf2f((u16)(u0 >> 16)) + c1.f * bf2f((u16)(u1 >> 16));
        }
        if (j < j1){
            u64 e0 = edata[j];
            union { u32 i; float f; } c0;
            c0.i = (u32)(e0 >> 32);
            u32 u0 = *(const u32*)&hin[(size_t)(u32)e0 * DH + col];
            ax += c0.f * bf2f((u16)u0);
            ay += c0.f * bf2f((u16)(u0 >> 16));
        }
        if (half == 0){   // self-loop + bias on the even wave
            float dn = dinv[node];
            float sc = dn * dn;
            u32 hu = *(const u32*)&hin[(size_t)node * DH + col];
            ax += bias[col]     + sc * bf2f((u16)hu);
            ay += bias[col + 1] + sc * bf2f((u16)(hu >> 16));
        }
    }
    if (half == 1){ part[local][lane][0] = ax; part[local][lane][1] = ay; }
    __syncthreads();
    if (half == 0 && node < N){
        ax += part[local][lane][0];
        ay += part[local][lane][1];
        *(u32*)&out[(size_t)node * DH + col] = pack2(ax, ay);
    }
}

// ---------------- batchnorm stats (bf16 input via u32 loads, f32 sums) ----------------

__global__ __launch_bounds__(256) void k_bnstats(const u16* __restrict__ h,
        float* sum, float* sq, int N, int rpb){
    __shared__ float rs[4][DH], rq[4][DH];
    int tid = threadIdx.x;
    int lane = tid & 63, wave = tid >> 6;
    int c = 2 * lane;
    int r0 = blockIdx.x * rpb;
    int r1 = r0 + rpb; if (r1 > N) r1 = N;
    float s0 = 0.0f, s1 = 0.0f, q0 = 0.0f, q1 = 0.0f;
    for (int r = r0 + wave; r < r1; r += 4){
        u32 u = *(const u32*)&h[(size_t)r * DH + c];
        float v0 = bf2f((u16)u), v1 = bf2f((u16)(u >> 16));
        s0 += v0; s1 += v1; q0 += v0 * v0; q1 += v1 * v1;
    }
    rs[wave][c] = s0; rs[wave][c + 1] = s1;
    rq[wave][c] = q0; rq[wave][c + 1] = q1;
    __syncthreads();
    if (tid < DH){
        atomicAdd(&sum[tid], rs[0][tid] + rs[1][tid] + rs[2][tid] + rs[3][tid]);
        atomicAdd(&sq[tid],  rq[0][tid] + rq[1][tid] + rq[2][tid] + rq[3][tid]);
    }
}

// ---------------- final: BN apply + leaky + residual + layernorm + store ----------------

__global__ __launch_bounds__(256) void k_lnf(const u16* __restrict__ B,
        const u16* __restrict__ R, const float* __restrict__ sum,
        const float* __restrict__ sq, const float* __restrict__ g,
        const float* __restrict__ be, float* __restrict__ out, int N, float invN){
    int node = blockIdx.x * 4 + (threadIdx.x >> 6);
    int lane = threadIdx.x & 63;
    if (node >= N) return;
    int col = 2 * lane;
    float2 sm  = *(const float2*)&sum[col];
    float2 sqv = *(const float2*)&sq[col];
    float2 gv  = *(const float2*)&g[col];
    float2 bev = *(const float2*)&be[col];
    float m0 = sm.x * invN, m1 = sm.y * invN;
    float va0 = sqv.x * invN - m0 * m0, va1 = sqv.y * invN - m1 * m1;
    float s0 = gv.x * rsqrtf(va0 + EPSF), s1 = gv.y * rsqrtf(va1 + EPSF);
    float h0 = bev.x - m0 * s0, h1 = bev.y - m1 * s1;
    u32 bu = *(const u32*)&B[(size_t)node * DH + col];
    u32 ru = *(const u32*)&R[(size_t)node * DH + col];
    float t0 = bf2f((u16)bu) * s0 + h0;
    t0 = ((t0 >= 0.0f) ? t0 : SLOPE * t0) + bf2f((u16)ru);
    float t1 = bf2f((u16)(bu >> 16)) * s1 + h1;
    t1 = ((t1 >= 0.0f) ? t1 : SLOPE * t1) + bf2f((u16)(ru >> 16));
    float s = t0 + t1;
    float q = t0 * t0 + t1 * t1;
    #pragma unroll
    for (int off = 1; off < 64; off <<= 1){
        s += __shfl_xor(s, off, 64);
        q += __shfl_xor(q, off, 64);
    }
    float mean = s * (1.0f / DH);
    float var  = q * (1.0f / DH) - mean * mean;
    float rstd = rsqrtf(var + EPSF);
    float2 o;
    o.x = (t0 - mean) * rstd;
    o.y = (t1 - mean) * rstd;
    *(float2*)&out[(size_t)node * DH + col] = o;
}

// ---------------- launch ----------------

extern "C" void kernel_launch(void* const* d_in, const int* in_sizes, int n_in,
                              void* d_out, int out_size, void* d_ws, size_t ws_size,
                              hipStream_t stream){
    const float* x    = (const float*)d_in[0];
    const int*   src  = (const int*)d_in[1];
    const int*   dst  = (const int*)d_in[2];
    const float* ew   = (const float*)d_in[3];
    const float* W0   = (const float*)d_in[4];
    const float* b0   = (const float*)d_in[5];
    const float* g0   = (const float*)d_in[6];
    const float* be0  = (const float*)d_in[7];
    const float* W1   = (const float*)d_in[8];
    const float* b1   = (const float*)d_in[9];
    const float* g1   = (const float*)d_in[10];
    const float* be1  = (const float*)d_in[11];
    const float* Wres = (const float*)d_in[12];
    const float* bres = (const float*)d_in[13];
    float* out = (float*)d_out;

    int N = in_sizes[0] / DIN;
    int E = in_sizes[1];
    size_t N128 = (size_t)N * DH;
    float invN = 1.0f / (float)N;

    // workspace layout
    u16* A = (u16*)d_ws;                 // gemm outputs, bf16 [N128]
    u16* B = A + N128;                   // agg outputs, bf16 [N128]
    u16* R = B + N128;                   // residual, bf16 [N128]
    u64* packed8 = (u64*)(R + N128);     // [8N] replicated histograms
    u64* edata   = packed8 + (size_t)NCOPY * N;   // [E] src | coef<<32
    float* dinv  = (float*)(edata + E);  // [N]
    int* rowst   = (int*)(dinv + N);     // [N+1]
    int* coff    = rowst + N + 1;        // [8N]
    int* slotl   = coff + (size_t)NCOPY * N;      // [E]
    float* stats = (float*)(slotl + E);  // 4*DH
    float* sum0 = stats,          *sq0 = stats + DH;
    float* sum1 = stats + 2 * DH, *sq1 = stats + 3 * DH;
    int* blocksum = (int*)(stats + 4 * DH);  // [ceil(N/1024)]

    int n8  = NCOPY * N;
    int ib  = (n8 + 255) / 256;
    int eb  = (E + 255) / 256;
    int gb  = (N + 15) / 16;
    int ab  = (N + 3) / 4;
    int kb  = (N + 1023) / 1024;
    int rpb = 250;
    int sb  = (N + rpb - 1) / rpb;

    k_init   <<<ib, 256, 0, stream>>>(packed8, stats, n8);
    k_count  <<<eb, 256, 0, stream>>>(dst, ew, packed8, slotl, E, N);
    k_scan1d <<<kb, 1024, 0, stream>>>(packed8, dinv, rowst, coff, blocksum, N);
    k_scan2  <<<1, 1024, 0, stream>>>(blocksum, rowst, kb, N, E);
    k_scan3  <<<kb, 1024, 0, stream>>>(rowst, blocksum, N);
    k_place  <<<eb, 256, 0, stream>>>(src, dst, ew, dinv, rowst, coff, slotl, edata, E, N);

    // layer 0
    k_gemm0    <<<gb, 256, 0, stream>>>(x, W0, Wres, bres, A, R, N);
    k_aggregate<<<ab, 512, 0, stream>>>(A, B, b0, dinv, rowst, edata, N);
    k_bnstats  <<<sb, 256, 0, stream>>>(B, sum0, sq0, N, rpb);

    // layer 1 (BN0+leaky+residual fused into gemm1 load)
    k_gemm1f   <<<gb, 256, 0, stream>>>(B, R, sum0, sq0, g0, be0, W1, A, N, invN);
    k_aggregate<<<ab, 512, 0, stream>>>(A, B, b1, dinv, rowst, edata, N);
    k_bnstats  <<<sb, 256, 0, stream>>>(B, sum1, sq1, N, rpb);

    // BN1+leaky+residual + layernorm fused
    k_lnf      <<<ab, 256, 0, stream>>>(B, R, sum1, sq1, g1, be1, out, N, invN);
}

// Round 8
// 345.421 us; speedup vs baseline: 1.2386x; 1.2386x over previous
//
#include <hip/hip_runtime.h>
#include <hip/hip_bf16.h>

#define DIN 64
#define DH 128
#define EPSF 1e-5f
#define SLOPE 0.1f

typedef unsigned short u16;
typedef unsigned int u32;
typedef unsigned long long u64;
typedef __attribute__((ext_vector_type(8))) short bf16x8;
typedef __attribute__((ext_vector_type(4))) float f32x4;

#define FIXS 16777216.0f   // 2^24 fixed-point scale for edge weights
#define LDA1 136           // padded LDS row stride (bf16) for K=128 tiles: 272B, 16B-aligned, 2-way bank alias (free)
#define LDA0 72            // padded LDS row stride for K=64 tiles: 144B

__device__ __forceinline__ float bf2f(u16 u){
    union { u32 i; float f; } v; v.i = ((u32)u) << 16; return v.f;
}
__device__ __forceinline__ u16 f2bf(float f){
    union { float f; u32 i; } v; v.f = f;
    u32 b = v.i;
    b += 0x7FFFu + ((b >> 16) & 1u);    // round to nearest even
    return (u16)(b >> 16);
}
__device__ __forceinline__ u32 pack2(float a, float b){
    return (u32)f2bf(a) | ((u32)f2bf(b) << 16);
}

// ---------------- graph prep ----------------

__global__ void k_init(u64* packed, float* stats, int N){
    int i = blockIdx.x * 256 + threadIdx.x;
    if (i < N) packed[i] = 0ull;
    if (i < 4 * DH) stats[i] = 0.0f;           // sum0, sq0, sum1, sq1
}

// ONE returning u64 atomic per edge: count in bits[40..], fixed-point ew sum in bits[0..40).
// Returned old count == slot-within-row (coalesced store).
__global__ void k_count(const int* __restrict__ dst, const float* __restrict__ ew,
                        u64* packed, int* __restrict__ slotl, int E){
    int e = blockIdx.x * 256 + threadIdx.x;
    if (e < E){
        int d = dst[e];
        u64 add = (1ull << 40) | (u64)(u32)__float2int_rn(ew[e] * FIXS);
        u64 old = atomicAdd(&packed[d], add);
        slotl[e] = (int)(old >> 40);
    }
}

// phase 1: per-1024-block exclusive scan of counts; fused dinv
__global__ __launch_bounds__(1024) void k_scan1d(const u64* __restrict__ packed,
        float* __restrict__ dinv, int* __restrict__ rowstart,
        int* __restrict__ blocksum, int N){
    __shared__ int lds[1024];
    int t = threadIdx.x;
    int i = blockIdx.x * 1024 + t;
    int v = 0;
    if (i < N){
        u64 p = packed[i];
        float deg = 1.0f + (float)(p & 0xFFFFFFFFFFull) * (1.0f / FIXS);
        dinv[i] = rsqrtf(deg);               // deg >= 1 (self-loop)
        v = (int)(p >> 40);
    }
    lds[t] = v;
    __syncthreads();
    for (int off = 1; off < 1024; off <<= 1){
        int add = (t >= off) ? lds[t - off] : 0;
        __syncthreads();
        lds[t] += add;
        __syncthreads();
    }
    if (i < N) rowstart[i] = lds[t] - v;            // block-local exclusive
    if (t == 1023) blocksum[blockIdx.x] = lds[1023];
}

// phase 2: scan block sums (nb <= 1024), set rowstart[N]
__global__ __launch_bounds__(1024) void k_scan2(int* __restrict__ blocksum,
        int* __restrict__ rowstart, int nb, int N, int E){
    __shared__ int lds[1024];
    int t = threadIdx.x;
    int v = (t < nb) ? blocksum[t] : 0;
    lds[t] = v;
    __syncthreads();
    for (int off = 1; off < 1024; off <<= 1){
        int add = (t >= off) ? lds[t - off] : 0;
        __syncthreads();
        lds[t] += add;
        __syncthreads();
    }
    if (t < nb) blocksum[t] = lds[t] - v;           // exclusive block offsets
    if (t == 0) rowstart[N] = E;
}

// phase 3: add block offsets
__global__ __launch_bounds__(1024) void k_scan3(int* __restrict__ rowstart,
        const int* __restrict__ blocksum, int N){
    int i = blockIdx.x * 1024 + threadIdx.x;
    if (i < N) rowstart[i] += blocksum[blockIdx.x];
}

// place edge data: slot = rowstart[d] + slotl[e]; NO atomics.
__global__ void k_place(const int* __restrict__ src, const int* __restrict__ dst,
                        const float* __restrict__ ew, const float* __restrict__ dinv,
                        const int* __restrict__ rowst, const int* __restrict__ slotl,
                        u64* __restrict__ edata, int E){
    int e = blockIdx.x * 256 + threadIdx.x;
    if (e < E){
        int s = src[e], d = dst[e];
        union { float f; u32 i; } c;
        c.f = dinv[s] * ew[e] * dinv[d];
        edata[(size_t)rowst[d] + slotl[e]] = (u64)(u32)s | ((u64)c.i << 32);
    }
}

// ---------------- GEMM 0 (MFMA bf16): h0 = x@W0, res = x@Wres + bres ----------------
// 64 rows/block, 256 out cols (W0|Wres). 4 waves x 16 rows. K=64.

__global__ __launch_bounds__(256) void k_gemm0(const float* __restrict__ x,
        const float* __restrict__ W0, const float* __restrict__ Wres,
        const float* __restrict__ bres, u16* __restrict__ h0,
        u16* __restrict__ res, int N){
    __shared__ u16 xs[64 * LDA0];    // 9 KB, x tile bf16
    __shared__ u16 ws[256 * LDA0];   // 36.9 KB, [n][k] transposed weights bf16
    int tid = threadIdx.x;
    int row0 = blockIdx.x * 64;
    // stage weights: [n][k], n = W0 col (n<128) or Wres col (n>=128)
    for (int i = tid; i < 256 * 32; i += 256){
        int n = i & 255, k = (i >> 8) * 2;
        int c = n & 127;
        const float* __restrict__ W = (n < 128) ? W0 : Wres;
        float wa = W[k * DH + c], wb = W[(k + 1) * DH + c];
        *(u32*)&ws[n * LDA0 + k] = pack2(wa, wb);
    }
    // stage x tile as bf16
    for (int i = tid; i < 64 * 32; i += 256){
        int r = i >> 5, k2 = (i & 31) * 2;
        int rr = row0 + r; if (rr >= N) rr = N - 1;
        float2 v = *(const float2*)&x[(size_t)rr * DIN + k2];
        *(u32*)&xs[r * LDA0 + k2] = pack2(v.x, v.y);
    }
    __syncthreads();
    int wave = tid >> 6, lane = tid & 63;
    int l15 = lane & 15, kq = (lane >> 4) * 8;
    f32x4 acc[16];
    #pragma unroll
    for (int nt = 0; nt < 16; nt++) acc[nt] = (f32x4){0.f, 0.f, 0.f, 0.f};
    #pragma unroll
    for (int kt = 0; kt < 2; kt++){
        int k0 = kt * 32 + kq;
        bf16x8 a = *(const bf16x8*)&xs[(wave * 16 + l15) * LDA0 + k0];
        #pragma unroll
        for (int nt = 0; nt < 16; nt++){
            bf16x8 b = *(const bf16x8*)&ws[(nt * 16 + l15) * LDA0 + k0];
            acc[nt] = __builtin_amdgcn_mfma_f32_16x16x32_bf16(a, b, acc[nt], 0, 0, 0);
        }
    }
    int rbase = row0 + wave * 16 + (lane >> 4) * 4;
    #pragma unroll
    for (int nt = 0; nt < 16; nt++){
        int col = nt * 16 + l15;
        #pragma unroll
        for (int reg = 0; reg < 4; reg++){
            int rr = rbase + reg;
            if (rr < N){
                if (col < DH) h0[(size_t)rr * DH + col] = f2bf(acc[nt][reg]);
                else          res[(size_t)rr * DH + (col - DH)] = f2bf(acc[nt][reg] + bres[col - DH]);
            }
        }
    }
}

// ---------------- GEMM 1 (MFMA bf16, fused BN+leaky+residual on input) ----------------
// A = (leaky(B*scale+shift)+R) @ W1.  64 rows/block, 128 cols, K=128.

__global__ __launch_bounds__(256) void k_gemm1f(const u16* __restrict__ Bi,
        const u16* __restrict__ Ri, const float* __restrict__ sum,
        const float* __restrict__ sq, const float* __restrict__ g,
        const float* __restrict__ be, const float* __restrict__ W1,
        u16* __restrict__ A, int N, float invN){
    __shared__ u16 xs[64 * LDA1];    // 17.4 KB
    __shared__ u16 ws[128 * LDA1];   // 34.8 KB, W1 transposed [n][k] bf16
    __shared__ float sc[DH], sh[DH];
    int tid = threadIdx.x;
    if (tid < DH){
        float mean = sum[tid] * invN;
        float var  = sq[tid] * invN - mean * mean;
        float s = g[tid] * rsqrtf(var + EPSF);
        sc[tid] = s;
        sh[tid] = be[tid] - mean * s;
    }
    // stage W1 transposed: ws[n][k]
    for (int i = tid; i < 128 * 64; i += 256){
        int n = i & 127, k = (i >> 7) * 2;
        float wa = W1[k * DH + n], wb = W1[(k + 1) * DH + n];
        *(u32*)&ws[n * LDA1 + k] = pack2(wa, wb);
    }
    __syncthreads();
    int row0 = blockIdx.x * 64;
    // stage input tile with BN+leaky+residual fused
    for (int i = tid; i < 64 * 64; i += 256){
        int r = i >> 6, k2 = (i & 63) * 2;
        int rr = row0 + r;
        u32 o = 0;
        if (rr < N){
            u32 bu = *(const u32*)&Bi[(size_t)rr * DH + k2];
            u32 ru = *(const u32*)&Ri[(size_t)rr * DH + k2];
            float t0 = bf2f((u16)bu) * sc[k2] + sh[k2];
            t0 = ((t0 >= 0.f) ? t0 : SLOPE * t0) + bf2f((u16)ru);
            float t1 = bf2f((u16)(bu >> 16)) * sc[k2 + 1] + sh[k2 + 1];
            t1 = ((t1 >= 0.f) ? t1 : SLOPE * t1) + bf2f((u16)(ru >> 16));
            o = pack2(t0, t1);
        }
        *(u32*)&xs[r * LDA1 + k2] = o;
    }
    __syncthreads();
    int wave = tid >> 6, lane = tid & 63;
    int l15 = lane & 15, kq = (lane >> 4) * 8;
    f32x4 acc[8];
    #pragma unroll
    for (int nt = 0; nt < 8; nt++) acc[nt] = (f32x4){0.f, 0.f, 0.f, 0.f};
    #pragma unroll
    for (int kt = 0; kt < 4; kt++){
        int k0 = kt * 32 + kq;
        bf16x8 a = *(const bf16x8*)&xs[(wave * 16 + l15) * LDA1 + k0];
        #pragma unroll
        for (int nt = 0; nt < 8; nt++){
            bf16x8 b = *(const bf16x8*)&ws[(nt * 16 + l15) * LDA1 + k0];
            acc[nt] = __builtin_amdgcn_mfma_f32_16x16x32_bf16(a, b, acc[nt], 0, 0, 0);
        }
    }
    int rbase = row0 + wave * 16 + (lane >> 4) * 4;
    #pragma unroll
    for (int nt = 0; nt < 8; nt++){
        int col = nt * 16 + l15;
        #pragma unroll
        for (int reg = 0; reg < 4; reg++){
            int rr = rbase + reg;
            if (rr < N) A[(size_t)rr * DH + col] = f2bf(acc[nt][reg]);
        }
    }
}

// ---------------- aggregation: one wave per node, 4 gather chains ----------------

__global__ __launch_bounds__(256) void k_aggregate(const u16* __restrict__ hin,
        u16* __restrict__ out, const float* __restrict__ bias,
        const float* __restrict__ dinv, const int* __restrict__ rowstart,
        const u64* __restrict__ edata, int N){
    int node = blockIdx.x * 4 + (threadIdx.x >> 6);
    int lane = threadIdx.x & 63;
    if (node >= N) return;
    float dn = dinv[node];
    float scf = dn * dn;                      // self-loop coefficient
    int col = 2 * lane;
    u32 hu = *(const u32*)&hin[(size_t)node * DH + col];
    float ax = bias[col]     + scf * bf2f((u16)hu);
    float ay = bias[col + 1] + scf * bf2f((u16)(hu >> 16));
    int rs = rowstart[node], re = rowstart[node + 1];
    int j = rs;
    for (; j + 3 < re; j += 4){
        u64 e0 = edata[j], e1 = edata[j + 1], e2 = edata[j + 2], e3 = edata[j + 3];
        union { u32 i; float f; } c0, c1, c2, c3;
        c0.i = (u32)(e0 >> 32); c1.i = (u32)(e1 >> 32);
        c2.i = (u32)(e2 >> 32); c3.i = (u32)(e3 >> 32);
        u32 u0 = *(const u32*)&hin[(size_t)(u32)e0 * DH + col];
        u32 u1 = *(const u32*)&hin[(size_t)(u32)e1 * DH + col];
        u32 u2 = *(const u32*)&hin[(size_t)(u32)e2 * DH + col];
        u32 u3 = *(const u32*)&hin[(size_t)(u32)e3 * DH + col];
        ax += c0.f * bf2f((u16)u0) + c1.f * bf2f((u16)u1)
            + c2.f * bf2f((u16)u2) + c3.f * bf2f((u16)u3);
        ay += c0.f * bf2f((u16)(u0 >> 16)) + c1.f * bf2f((u16)(u1 >> 16))
            + c2.f * bf2f((u16)(u2 >> 16)) + c3.f * bf2f((u16)(u3 >> 16));
    }
    for (; j < re; j++){
        u64 e0 = edata[j];
        union { u32 i; float f; } c0;
        c0.i = (u32)(e0 >> 32);
        u32 u0 = *(const u32*)&hin[(size_t)(u32)e0 * DH + col];
        ax += c0.f * bf2f((u16)u0);
        ay += c0.f * bf2f((u16)(u0 >> 16));
    }
    *(u32*)&out[(size_t)node * DH + col] = pack2(ax, ay);
}

// ---------------- batchnorm stats (bf16 input via u32 loads, f32 sums) ----------------

__global__ __launch_bounds__(256) void k_bnstats(const u16* __restrict__ h,
        float* sum, float* sq, int N, int rpb){
    __shared__ float rs[4][DH], rq[4][DH];
    int tid = threadIdx.x;
    int lane = tid & 63, wave = tid >> 6;
    int c = 2 * lane;
    int r0 = blockIdx.x * rpb;
    int r1 = r0 + rpb; if (r1 > N) r1 = N;
    float s0 = 0.0f, s1 = 0.0f, q0 = 0.0f, q1 = 0.0f;
    for (int r = r0 + wave; r < r1; r += 4){
        u32 u = *(const u32*)&h[(size_t)r * DH + c];
        float v0 = bf2f((u16)u), v1 = bf2f((u16)(u >> 16));
        s0 += v0; s1 += v1; q0 += v0 * v0; q1 += v1 * v1;
    }
    rs[wave][c] = s0; rs[wave][c + 1] = s1;
    rq[wave][c] = q0; rq[wave][c + 1] = q1;
    __syncthreads();
    if (tid < DH){
        atomicAdd(&sum[tid], rs[0][tid] + rs[1][tid] + rs[2][tid] + rs[3][tid]);
        atomicAdd(&sq[tid],  rq[0][tid] + rq[1][tid] + rq[2][tid] + rq[3][tid]);
    }
}

// ---------------- final: BN apply + leaky + residual + layernorm + store ----------------

__global__ __launch_bounds__(256) void k_lnf(const u16* __restrict__ B,
        const u16* __restrict__ R, const float* __restrict__ sum,
        const float* __restrict__ sq, const float* __restrict__ g,
        const float* __restrict__ be, float* __restrict__ out, int N, float invN){
    int node = blockIdx.x * 4 + (threadIdx.x >> 6);
    int lane = threadIdx.x & 63;
    if (node >= N) return;
    int col = 2 * lane;
    float2 sm  = *(const float2*)&sum[col];
    float2 sqv = *(const float2*)&sq[col];
    float2 gv  = *(const float2*)&g[col];
    float2 bev = *(const float2*)&be[col];
    float m0 = sm.x * invN, m1 = sm.y * invN;
    float va0 = sqv.x * invN - m0 * m0, va1 = sqv.y * invN - m1 * m1;
    float s0 = gv.x * rsqrtf(va0 + EPSF), s1 = gv.y * rsqrtf(va1 + EPSF);
    float h0 = bev.x - m0 * s0, h1 = bev.y - m1 * s1;
    u32 bu = *(const u32*)&B[(size_t)node * DH + col];
    u32 ru = *(const u32*)&R[(size_t)node * DH + col];
    float t0 = bf2f((u16)bu) * s0 + h0;
    t0 = ((t0 >= 0.0f) ? t0 : SLOPE * t0) + bf2f((u16)ru);
    float t1 = bf2f((u16)(bu >> 16)) * s1 + h1;
    t1 = ((t1 >= 0.0f) ? t1 : SLOPE * t1) + bf2f((u16)(ru >> 16));
    float s = t0 + t1;
    float q = t0 * t0 + t1 * t1;
    #pragma unroll
    for (int off = 1; off < 64; off <<= 1){
        s += __shfl_xor(s, off, 64);
        q += __shfl_xor(q, off, 64);
    }
    float mean = s * (1.0f / DH);
    float var  = q * (1.0f / DH) - mean * mean;
    float rstd = rsqrtf(var + EPSF);
    float2 o;
    o.x = (t0 - mean) * rstd;
    o.y = (t1 - mean) * rstd;
    *(float2*)&out[(size_t)node * DH + col] = o;
}

// ---------------- launch ----------------

extern "C" void kernel_launch(void* const* d_in, const int* in_sizes, int n_in,
                              void* d_out, int out_size, void* d_ws, size_t ws_size,
                              hipStream_t stream){
    const float* x    = (const float*)d_in[0];
    const int*   src  = (const int*)d_in[1];
    const int*   dst  = (const int*)d_in[2];
    const float* ew   = (const float*)d_in[3];
    const float* W0   = (const float*)d_in[4];
    const float* b0   = (const float*)d_in[5];
    const float* g0   = (const float*)d_in[6];
    const float* be0  = (const float*)d_in[7];
    const float* W1   = (const float*)d_in[8];
    const float* b1   = (const float*)d_in[9];
    const float* g1   = (const float*)d_in[10];
    const float* be1  = (const float*)d_in[11];
    const float* Wres = (const float*)d_in[12];
    const float* bres = (const float*)d_in[13];
    float* out = (float*)d_out;

    int N = in_sizes[0] / DIN;
    int E = in_sizes[1];
    size_t N128 = (size_t)N * DH;
    float invN = 1.0f / (float)N;

    // workspace layout
    u16* A = (u16*)d_ws;                 // gemm outputs, bf16 [N128]
    u16* B = A + N128;                   // agg outputs, bf16 [N128]
    u16* R = B + N128;                   // residual, bf16 [N128]
    u64* packed = (u64*)(R + N128);      // [N] count<<40 | fixed ew sum
    u64* edata  = packed + N;            // [E] src | coef<<32
    float* dinv = (float*)(edata + E);   // [N]
    int* rowst  = (int*)(dinv + N);      // [N+1]
    int* slotl  = rowst + N + 1;         // [E]
    float* stats = (float*)(slotl + E);  // 4*DH
    float* sum0 = stats,          *sq0 = stats + DH;
    float* sum1 = stats + 2 * DH, *sq1 = stats + 3 * DH;
    int* blocksum = (int*)(stats + 4 * DH);  // [ceil(N/1024)]

    int nb  = (N + 255) / 256;
    int eb  = (E + 255) / 256;
    int gb  = (N + 63) / 64;
    int ab  = (N + 3) / 4;
    int kb  = (N + 1023) / 1024;
    int rpb = 250;
    int sb  = (N + rpb - 1) / rpb;

    k_init   <<<nb, 256, 0, stream>>>(packed, stats, N);
    k_count  <<<eb, 256, 0, stream>>>(dst, ew, packed, slotl, E);
    k_scan1d <<<kb, 1024, 0, stream>>>(packed, dinv, rowst, blocksum, N);
    k_scan2  <<<1, 1024, 0, stream>>>(blocksum, rowst, kb, N, E);
    k_scan3  <<<kb, 1024, 0, stream>>>(rowst, blocksum, N);
    k_place  <<<eb, 256, 0, stream>>>(src, dst, ew, dinv, rowst, slotl, edata, E);

    // layer 0
    k_gemm0    <<<gb, 256, 0, stream>>>(x, W0, Wres, bres, A, R, N);
    k_aggregate<<<ab, 256, 0, stream>>>(A, B, b0, dinv, rowst, edata, N);
    k_bnstats  <<<sb, 256, 0, stream>>>(B, sum0, sq0, N, rpb);

    // layer 1 (BN0+leaky+residual fused into gemm1 tile load)
    k_gemm1f   <<<gb, 256, 0, stream>>>(B, R, sum0, sq0, g0, be0, W1, A, N, invN);
    k_aggregate<<<ab, 256, 0, stream>>>(A, B, b1, dinv, rowst, edata, N);
    k_bnstats  <<<sb, 256, 0, stream>>>(B, sum1, sq1, N, rpb);

    // BN1+leaky+residual + layernorm fused
    k_lnf      <<<ab, 256, 0, stream>>>(B, R, sum1, sq1, g1, be1, out, N, invN);
}

// Round 9
// 337.776 us; speedup vs baseline: 1.2666x; 1.0226x over previous
//
#include <hip/hip_runtime.h>
#include <hip/hip_bf16.h>

#define DIN 64
#define DH 128
#define EPSF 1e-5f
#define SLOPE 0.1f

typedef unsigned short u16;
typedef unsigned int u32;
typedef unsigned long long u64;
typedef __attribute__((ext_vector_type(8))) short bf16x8;
typedef __attribute__((ext_vector_type(4))) float f32x4;

#define FIXS 16777216.0f   // 2^24 fixed-point scale for edge weights
#define LDA1 136           // padded LDS row stride (bf16), K=128 tiles
#define LDA0 72            // padded LDS row stride, K=64 tiles

__device__ __forceinline__ float bf2f(u16 u){
    union { u32 i; float f; } v; v.i = ((u32)u) << 16; return v.f;
}
__device__ __forceinline__ u16 f2bf(float f){
    union { float f; u32 i; } v; v.f = f;
    u32 b = v.i;
    b += 0x7FFFu + ((b >> 16) & 1u);    // round to nearest even
    return (u16)(b >> 16);
}
__device__ __forceinline__ u32 pack2(float a, float b){
    return (u32)f2bf(a) | ((u32)f2bf(b) << 16);
}

// ---------------- graph prep ----------------

__global__ void k_init(u64* packed, float* stats, int N){
    int i = blockIdx.x * 256 + threadIdx.x;
    if (i < N) packed[i] = 0ull;
    if (i < 4 * DH) stats[i] = 0.0f;           // sum0, sq0, sum1, sq1
}

// ONE returning u64 atomic per edge; 4 edges/thread so 4 atomics are in flight
// per wave (latency-bound otherwise: ~600cyc atomic latency / ~17 waves/CU).
__global__ void k_count(const int* __restrict__ dst, const float* __restrict__ ew,
                        u64* packed, int* __restrict__ slotl, int E){
    int base = blockIdx.x * 1024 + threadIdx.x;
    int e0 = base, e1 = base + 256, e2 = base + 512, e3 = base + 768;
    int d0 = 0, d1 = 0, d2 = 0, d3 = 0;
    float w0 = 0, w1 = 0, w2 = 0, w3 = 0;
    bool v0 = e0 < E, v1 = e1 < E, v2 = e2 < E, v3 = e3 < E;
    if (v0){ d0 = dst[e0]; w0 = ew[e0]; }
    if (v1){ d1 = dst[e1]; w1 = ew[e1]; }
    if (v2){ d2 = dst[e2]; w2 = ew[e2]; }
    if (v3){ d3 = dst[e3]; w3 = ew[e3]; }
    u64 o0 = 0, o1 = 0, o2 = 0, o3 = 0;
    if (v0) o0 = atomicAdd(&packed[d0], (1ull << 40) | (u64)(u32)__float2int_rn(w0 * FIXS));
    if (v1) o1 = atomicAdd(&packed[d1], (1ull << 40) | (u64)(u32)__float2int_rn(w1 * FIXS));
    if (v2) o2 = atomicAdd(&packed[d2], (1ull << 40) | (u64)(u32)__float2int_rn(w2 * FIXS));
    if (v3) o3 = atomicAdd(&packed[d3], (1ull << 40) | (u64)(u32)__float2int_rn(w3 * FIXS));
    if (v0) slotl[e0] = (int)(o0 >> 40);
    if (v1) slotl[e1] = (int)(o1 >> 40);
    if (v2) slotl[e2] = (int)(o2 >> 40);
    if (v3) slotl[e3] = (int)(o3 >> 40);
}

// phase 1: per-1024-block exclusive scan of counts; fused dinv
__global__ __launch_bounds__(1024) void k_scan1d(const u64* __restrict__ packed,
        float* __restrict__ dinv, int* __restrict__ rowstart,
        int* __restrict__ blocksum, int N){
    __shared__ int lds[1024];
    int t = threadIdx.x;
    int i = blockIdx.x * 1024 + t;
    int v = 0;
    if (i < N){
        u64 p = packed[i];
        float deg = 1.0f + (float)(p & 0xFFFFFFFFFFull) * (1.0f / FIXS);
        dinv[i] = rsqrtf(deg);               // deg >= 1 (self-loop)
        v = (int)(p >> 40);
    }
    lds[t] = v;
    __syncthreads();
    for (int off = 1; off < 1024; off <<= 1){
        int add = (t >= off) ? lds[t - off] : 0;
        __syncthreads();
        lds[t] += add;
        __syncthreads();
    }
    if (i < N) rowstart[i] = lds[t] - v;            // block-local exclusive
    if (t == 1023) blocksum[blockIdx.x] = lds[1023];
}

// phase 2: scan block sums (nb <= 1024), set rowstart[N]
__global__ __launch_bounds__(1024) void k_scan2(int* __restrict__ blocksum,
        int* __restrict__ rowstart, int nb, int N, int E){
    __shared__ int lds[1024];
    int t = threadIdx.x;
    int v = (t < nb) ? blocksum[t] : 0;
    lds[t] = v;
    __syncthreads();
    for (int off = 1; off < 1024; off <<= 1){
        int add = (t >= off) ? lds[t - off] : 0;
        __syncthreads();
        lds[t] += add;
        __syncthreads();
    }
    if (t < nb) blocksum[t] = lds[t] - v;           // exclusive block offsets
    if (t == 0) rowstart[N] = E;
}

// phase 3: add block offsets
__global__ __launch_bounds__(1024) void k_scan3(int* __restrict__ rowstart,
        const int* __restrict__ blocksum, int N){
    int i = blockIdx.x * 1024 + threadIdx.x;
    if (i < N) rowstart[i] += blocksum[blockIdx.x];
}

// place edge data, 4 edges/thread (8 dinv-gather chains in flight); NO atomics.
__global__ void k_place(const int* __restrict__ src, const int* __restrict__ dst,
                        const float* __restrict__ ew, const float* __restrict__ dinv,
                        const int* __restrict__ rowst, const int* __restrict__ slotl,
                        u64* __restrict__ edata, int E){
    int base = blockIdx.x * 1024 + threadIdx.x;
    #pragma unroll
    for (int u = 0; u < 4; u++){
        int e = base + u * 256;
        if (e < E){
            int s = src[e], d = dst[e];
            union { float f; u32 i; } c;
            c.f = dinv[s] * ew[e] * dinv[d];
            edata[(size_t)rowst[d] + slotl[e]] = (u64)(u32)s | ((u64)c.i << 32);
        }
    }
}

// ---------------- GEMM 0 (MFMA bf16): h0 = x@W0, res = x@Wres + bres ----------------
// 64 rows/block, 256 out cols (W0|Wres). 4 waves x 16 rows. K=64.

__global__ __launch_bounds__(256) void k_gemm0(const float* __restrict__ x,
        const float* __restrict__ W0, const float* __restrict__ Wres,
        const float* __restrict__ bres, u16* __restrict__ h0,
        u16* __restrict__ res, int N){
    __shared__ u16 xs[64 * LDA0];    // 9 KB
    __shared__ u16 ws[256 * LDA0];   // 36.9 KB, [n][k] transposed weights bf16
    int tid = threadIdx.x;
    int row0 = blockIdx.x * 64;
    for (int i = tid; i < 256 * 32; i += 256){
        int n = i & 255, k = (i >> 8) * 2;
        int c = n & 127;
        const float* __restrict__ W = (n < 128) ? W0 : Wres;
        float wa = W[k * DH + c], wb = W[(k + 1) * DH + c];
        *(u32*)&ws[n * LDA0 + k] = pack2(wa, wb);
    }
    for (int i = tid; i < 64 * 32; i += 256){
        int r = i >> 5, k2 = (i & 31) * 2;
        int rr = row0 + r; if (rr >= N) rr = N - 1;
        float2 v = *(const float2*)&x[(size_t)rr * DIN + k2];
        *(u32*)&xs[r * LDA0 + k2] = pack2(v.x, v.y);
    }
    __syncthreads();
    int wave = tid >> 6, lane = tid & 63;
    int l15 = lane & 15, kq = (lane >> 4) * 8;
    f32x4 acc[16];
    #pragma unroll
    for (int nt = 0; nt < 16; nt++) acc[nt] = (f32x4){0.f, 0.f, 0.f, 0.f};
    #pragma unroll
    for (int kt = 0; kt < 2; kt++){
        int k0 = kt * 32 + kq;
        bf16x8 a = *(const bf16x8*)&xs[(wave * 16 + l15) * LDA0 + k0];
        #pragma unroll
        for (int nt = 0; nt < 16; nt++){
            bf16x8 b = *(const bf16x8*)&ws[(nt * 16 + l15) * LDA0 + k0];
            acc[nt] = __builtin_amdgcn_mfma_f32_16x16x32_bf16(a, b, acc[nt], 0, 0, 0);
        }
    }
    int rbase = row0 + wave * 16 + (lane >> 4) * 4;
    #pragma unroll
    for (int nt = 0; nt < 16; nt++){
        int col = nt * 16 + l15;
        #pragma unroll
        for (int reg = 0; reg < 4; reg++){
            int rr = rbase + reg;
            if (rr < N){
                if (col < DH) h0[(size_t)rr * DH + col] = f2bf(acc[nt][reg]);
                else          res[(size_t)rr * DH + (col - DH)] = f2bf(acc[nt][reg] + bres[col - DH]);
            }
        }
    }
}

// ---------------- GEMM 1 (MFMA bf16, fused BN+leaky+residual on input) ----------------

__global__ __launch_bounds__(256) void k_gemm1f(const u16* __restrict__ Bi,
        const u16* __restrict__ Ri, const float* __restrict__ sum,
        const float* __restrict__ sq, const float* __restrict__ g,
        const float* __restrict__ be, const float* __restrict__ W1,
        u16* __restrict__ A, int N, float invN){
    __shared__ u16 xs[64 * LDA1];    // 17.4 KB
    __shared__ u16 ws[128 * LDA1];   // 34.8 KB
    __shared__ float sc[DH], sh[DH];
    int tid = threadIdx.x;
    if (tid < DH){
        float mean = sum[tid] * invN;
        float var  = sq[tid] * invN - mean * mean;
        float s = g[tid] * rsqrtf(var + EPSF);
        sc[tid] = s;
        sh[tid] = be[tid] - mean * s;
    }
    for (int i = tid; i < 128 * 64; i += 256){
        int n = i & 127, k = (i >> 7) * 2;
        float wa = W1[k * DH + n], wb = W1[(k + 1) * DH + n];
        *(u32*)&ws[n * LDA1 + k] = pack2(wa, wb);
    }
    __syncthreads();
    int row0 = blockIdx.x * 64;
    for (int i = tid; i < 64 * 64; i += 256){
        int r = i >> 6, k2 = (i & 63) * 2;
        int rr = row0 + r;
        u32 o = 0;
        if (rr < N){
            u32 bu = *(const u32*)&Bi[(size_t)rr * DH + k2];
            u32 ru = *(const u32*)&Ri[(size_t)rr * DH + k2];
            float t0 = bf2f((u16)bu) * sc[k2] + sh[k2];
            t0 = ((t0 >= 0.f) ? t0 : SLOPE * t0) + bf2f((u16)ru);
            float t1 = bf2f((u16)(bu >> 16)) * sc[k2 + 1] + sh[k2 + 1];
            t1 = ((t1 >= 0.f) ? t1 : SLOPE * t1) + bf2f((u16)(ru >> 16));
            o = pack2(t0, t1);
        }
        *(u32*)&xs[r * LDA1 + k2] = o;
    }
    __syncthreads();
    int wave = tid >> 6, lane = tid & 63;
    int l15 = lane & 15, kq = (lane >> 4) * 8;
    f32x4 acc[8];
    #pragma unroll
    for (int nt = 0; nt < 8; nt++) acc[nt] = (f32x4){0.f, 0.f, 0.f, 0.f};
    #pragma unroll
    for (int kt = 0; kt < 4; kt++){
        int k0 = kt * 32 + kq;
        bf16x8 a = *(const bf16x8*)&xs[(wave * 16 + l15) * LDA1 + k0];
        #pragma unroll
        for (int nt = 0; nt < 8; nt++){
            bf16x8 b = *(const bf16x8*)&ws[(nt * 16 + l15) * LDA1 + k0];
            acc[nt] = __builtin_amdgcn_mfma_f32_16x16x32_bf16(a, b, acc[nt], 0, 0, 0);
        }
    }
    int rbase = row0 + wave * 16 + (lane >> 4) * 4;
    #pragma unroll
    for (int nt = 0; nt < 8; nt++){
        int col = nt * 16 + l15;
        #pragma unroll
        for (int reg = 0; reg < 4; reg++){
            int rr = rbase + reg;
            if (rr < N) A[(size_t)rr * DH + col] = f2bf(acc[nt][reg]);
        }
    }
}

// ---------------- aggregation: one wave per node, 8 gather chains ----------------

__device__ __forceinline__ void agg_edge(const u16* __restrict__ hin, u64 e,
                                         int col, float& ax, float& ay){
    union { u32 i; float f; } c;
    c.i = (u32)(e >> 32);
    u32 u = *(const u32*)&hin[(size_t)(u32)e * DH + col];
    ax += c.f * bf2f((u16)u);
    ay += c.f * bf2f((u16)(u >> 16));
}

__global__ __launch_bounds__(256) void k_aggregate(const u16* __restrict__ hin,
        u16* __restrict__ out, const float* __restrict__ bias,
        const float* __restrict__ dinv, const int* __restrict__ rowstart,
        const u64* __restrict__ edata, int N){
    int node = blockIdx.x * 4 + (threadIdx.x >> 6);
    int lane = threadIdx.x & 63;
    if (node >= N) return;
    float dn = dinv[node];
    float scf = dn * dn;                      // self-loop coefficient
    int col = 2 * lane;
    u32 hu = *(const u32*)&hin[(size_t)node * DH + col];
    float ax = bias[col]     + scf * bf2f((u16)hu);
    float ay = bias[col + 1] + scf * bf2f((u16)(hu >> 16));
    int rs = rowstart[node], re = rowstart[node + 1];
    int j = rs;
    for (; j + 7 < re; j += 8){
        u64 e0 = edata[j],     e1 = edata[j + 1], e2 = edata[j + 2], e3 = edata[j + 3];
        u64 e4 = edata[j + 4], e5 = edata[j + 5], e6 = edata[j + 6], e7 = edata[j + 7];
        agg_edge(hin, e0, col, ax, ay); agg_edge(hin, e1, col, ax, ay);
        agg_edge(hin, e2, col, ax, ay); agg_edge(hin, e3, col, ax, ay);
        agg_edge(hin, e4, col, ax, ay); agg_edge(hin, e5, col, ax, ay);
        agg_edge(hin, e6, col, ax, ay); agg_edge(hin, e7, col, ax, ay);
    }
    if (j + 3 < re){
        u64 e0 = edata[j], e1 = edata[j + 1], e2 = edata[j + 2], e3 = edata[j + 3];
        agg_edge(hin, e0, col, ax, ay); agg_edge(hin, e1, col, ax, ay);
        agg_edge(hin, e2, col, ax, ay); agg_edge(hin, e3, col, ax, ay);
        j += 4;
    }
    for (; j < re; j++){
        u64 e0 = edata[j];
        agg_edge(hin, e0, col, ax, ay);
    }
    *(u32*)&out[(size_t)node * DH + col] = pack2(ax, ay);
}

// ---------------- batchnorm stats (bf16 input via u32 loads, f32 sums) ----------------

__global__ __launch_bounds__(256) void k_bnstats(const u16* __restrict__ h,
        float* sum, float* sq, int N, int rpb){
    __shared__ float rs[4][DH], rq[4][DH];
    int tid = threadIdx.x;
    int lane = tid & 63, wave = tid >> 6;
    int c = 2 * lane;
    int r0 = blockIdx.x * rpb;
    int r1 = r0 + rpb; if (r1 > N) r1 = N;
    float s0 = 0.0f, s1 = 0.0f, q0 = 0.0f, q1 = 0.0f;
    for (int r = r0 + wave; r < r1; r += 4){
        u32 u = *(const u32*)&h[(size_t)r * DH + c];
        float v0 = bf2f((u16)u), v1 = bf2f((u16)(u >> 16));
        s0 += v0; s1 += v1; q0 += v0 * v0; q1 += v1 * v1;
    }
    rs[wave][c] = s0; rs[wave][c + 1] = s1;
    rq[wave][c] = q0; rq[wave][c + 1] = q1;
    __syncthreads();
    if (tid < DH){
        atomicAdd(&sum[tid], rs[0][tid] + rs[1][tid] + rs[2][tid] + rs[3][tid]);
        atomicAdd(&sq[tid],  rq[0][tid] + rq[1][tid] + rq[2][tid] + rq[3][tid]);
    }
}

// ---------------- final: BN apply + leaky + residual + layernorm + store ----------------

__global__ __launch_bounds__(256) void k_lnf(const u16* __restrict__ B,
        const u16* __restrict__ R, const float* __restrict__ sum,
        const float* __restrict__ sq, const float* __restrict__ g,
        const float* __restrict__ be, float* __restrict__ out, int N, float invN){
    int node = blockIdx.x * 4 + (threadIdx.x >> 6);
    int lane = threadIdx.x & 63;
    if (node >= N) return;
    int col = 2 * lane;
    float2 sm  = *(const float2*)&sum[col];
    float2 sqv = *(const float2*)&sq[col];
    float2 gv  = *(const float2*)&g[col];
    float2 bev = *(const float2*)&be[col];
    float m0 = sm.x * invN, m1 = sm.y * invN;
    float va0 = sqv.x * invN - m0 * m0, va1 = sqv.y * invN - m1 * m1;
    float s0 = gv.x * rsqrtf(va0 + EPSF), s1 = gv.y * rsqrtf(va1 + EPSF);
    float h0 = bev.x - m0 * s0, h1 = bev.y - m1 * s1;
    u32 bu = *(const u32*)&B[(size_t)node * DH + col];
    u32 ru = *(const u32*)&R[(size_t)node * DH + col];
    float t0 = bf2f((u16)bu) * s0 + h0;
    t0 = ((t0 >= 0.0f) ? t0 : SLOPE * t0) + bf2f((u16)ru);
    float t1 = bf2f((u16)(bu >> 16)) * s1 + h1;
    t1 = ((t1 >= 0.0f) ? t1 : SLOPE * t1) + bf2f((u16)(ru >> 16));
    float s = t0 + t1;
    float q = t0 * t0 + t1 * t1;
    #pragma unroll
    for (int off = 1; off < 64; off <<= 1){
        s += __shfl_xor(s, off, 64);
        q += __shfl_xor(q, off, 64);
    }
    float mean = s * (1.0f / DH);
    float var  = q * (1.0f / DH) - mean * mean;
    float rstd = rsqrtf(var + EPSF);
    float2 o;
    o.x = (t0 - mean) * rstd;
    o.y = (t1 - mean) * rstd;
    *(float2*)&out[(size_t)node * DH + col] = o;
}

// ---------------- launch ----------------

extern "C" void kernel_launch(void* const* d_in, const int* in_sizes, int n_in,
                              void* d_out, int out_size, void* d_ws, size_t ws_size,
                              hipStream_t stream){
    const float* x    = (const float*)d_in[0];
    const int*   src  = (const int*)d_in[1];
    const int*   dst  = (const int*)d_in[2];
    const float* ew   = (const float*)d_in[3];
    const float* W0   = (const float*)d_in[4];
    const float* b0   = (const float*)d_in[5];
    const float* g0   = (const float*)d_in[6];
    const float* be0  = (const float*)d_in[7];
    const float* W1   = (const float*)d_in[8];
    const float* b1   = (const float*)d_in[9];
    const float* g1   = (const float*)d_in[10];
    const float* be1  = (const float*)d_in[11];
    const float* Wres = (const float*)d_in[12];
    const float* bres = (const float*)d_in[13];
    float* out = (float*)d_out;

    int N = in_sizes[0] / DIN;
    int E = in_sizes[1];
    size_t N128 = (size_t)N * DH;
    float invN = 1.0f / (float)N;

    // workspace layout
    u16* A = (u16*)d_ws;                 // gemm outputs, bf16 [N128]
    u16* B = A + N128;                   // agg outputs, bf16 [N128]
    u16* R = B + N128;                   // residual, bf16 [N128]
    u64* packed = (u64*)(R + N128);      // [N] count<<40 | fixed ew sum
    u64* edata  = packed + N;            // [E] src | coef<<32
    float* dinv = (float*)(edata + E);   // [N]
    int* rowst  = (int*)(dinv + N);      // [N+1]
    int* slotl  = rowst + N + 1;         // [E]
    float* stats = (float*)(slotl + E);  // 4*DH
    float* sum0 = stats,          *sq0 = stats + DH;
    float* sum1 = stats + 2 * DH, *sq1 = stats + 3 * DH;
    int* blocksum = (int*)(stats + 4 * DH);  // [ceil(N/1024)]

    int nb  = (N + 255) / 256;
    int eb4 = (E + 1023) / 1024;
    int gb  = (N + 63) / 64;
    int ab  = (N + 3) / 4;
    int kb  = (N + 1023) / 1024;
    int rpb = 250;
    int sb  = (N + rpb - 1) / rpb;

    k_init   <<<nb, 256, 0, stream>>>(packed, stats, N);
    k_count  <<<eb4, 256, 0, stream>>>(dst, ew, packed, slotl, E);
    k_scan1d <<<kb, 1024, 0, stream>>>(packed, dinv, rowst, blocksum, N);
    k_scan2  <<<1, 1024, 0, stream>>>(blocksum, rowst, kb, N, E);
    k_scan3  <<<kb, 1024, 0, stream>>>(rowst, blocksum, N);
    k_place  <<<eb4, 256, 0, stream>>>(src, dst, ew, dinv, rowst, slotl, edata, E);

    // layer 0
    k_gemm0    <<<gb, 256, 0, stream>>>(x, W0, Wres, bres, A, R, N);
    k_aggregate<<<ab, 256, 0, stream>>>(A, B, b0, dinv, rowst, edata, N);
    k_bnstats  <<<sb, 256, 0, stream>>>(B, sum0, sq0, N, rpb);

    // layer 1 (BN0+leaky+residual fused into gemm1 tile load)
    k_gemm1f   <<<gb, 256, 0, stream>>>(B, R, sum0, sq0, g0, be0, W1, A, N, invN);
    k_aggregate<<<ab, 256, 0, stream>>>(A, B, b1, dinv, rowst, edata, N);
    k_bnstats  <<<sb, 256, 0, stream>>>(B, sum1, sq1, N, rpb);

    // BN1+leaky+residual + layernorm fused
    k_lnf      <<<ab, 256, 0, stream>>>(B, R, sum1, sq1, g1, be1, out, N, invN);
}